// Round 6
// baseline (1747.941 us; speedup 1.0000x reference)
//
#include <hip/hip_runtime.h>
#include <cstdint>
#include <cstddef>

#define B_ 32
#define NS_ 4096
#define D_ 256
#define H_ 4
#define L_ 6
#define NQ_ 512
#define NK_ 1024
#define DH_ 64
#define SCALE_ 0.125f

typedef unsigned short ushort_t;
typedef unsigned long long u64_t;
typedef __bf16 bf16x8 __attribute__((ext_vector_type(8)));
typedef float f32x4 __attribute__((ext_vector_type(4)));

__device__ __forceinline__ ushort_t f2bf(float f) {
  unsigned u = __float_as_uint(f);
  u += 0x7fffu + ((u >> 16) & 1u);
  return (ushort_t)(u >> 16);
}

// async global->LDS, 16B per lane. lds ptr must be wave-uniform (HW adds lane*16).
__device__ __forceinline__ void gld16(const void* g, void* l) {
  __builtin_amdgcn_global_load_lds(
      (__attribute__((address_space(1))) void*)(uintptr_t)g,
      (__attribute__((address_space(3))) void*)(uintptr_t)l, 16, 0, 0);
}

// ---------------- weight prep: Wt[n][k] = bf16(W[k][n]) ----------------
__global__ __launch_bounds__(256) void prep_w(
    const float* __restrict__ w0, const float* __restrict__ w1,
    const float* __restrict__ w2, const float* __restrict__ w3,
    const float* __restrict__ w4, const float* __restrict__ w5,
    ushort_t* __restrict__ wt) {
  const int sel = blockIdx.x >> 8;
  const int n = blockIdx.x & 255;
  const int k = threadIdx.x;
  const float* W = sel == 0 ? w0 : sel == 1 ? w1 : sel == 2 ? w2
                 : sel == 3 ? w3 : sel == 4 ? w4 : w5;
  wt[sel * 65536 + n * 256 + k] = f2bf(W[k * 256 + n]);
}

// ---------------- mask prep: pack (maskl > 0.5) into bits, 1 u64 per 64 cols ----
__global__ __launch_bounds__(256) void prep_mask(
    const float* __restrict__ ml, u64_t* __restrict__ mb) {
  const long gid = (long)blockIdx.x * 256 + threadIdx.x;  // over L*NQ*NK
  const bool m = ml[gid] > 0.5f;
  const u64_t bal = __ballot(m);
  if ((threadIdx.x & 63) == 0) mb[gid >> 6] = bal;
}

// ---------------- gather + sys LayerNorm -> bf16 (one WAVE per row) ----------------
// lane loads float4 (cols lane*4..+3); 6-step shfl_xor reduce; no LDS, no barriers.
__global__ __launch_bounds__(256) void gather_ln(
    const float* __restrict__ ut, const float* __restrict__ emb,
    const int* __restrict__ qidx, const int* __restrict__ kidx,
    const float* __restrict__ sc, const float* __restrict__ bi,
    ushort_t* __restrict__ qn, ushort_t* __restrict__ kn) {
  const int w = threadIdx.x >> 6, lane = threadIdx.x & 63;
  const int R = blockIdx.x * 4 + w;
  int bb, idx;
  ushort_t* dst;
  long drow;
  if (R < B_ * NQ_) {
    bb = R >> 9; idx = qidx[R & (NQ_ - 1)]; dst = qn; drow = R;
  } else {
    const int r2 = R - B_ * NQ_;
    bb = r2 >> 10; idx = kidx[r2 & (NK_ - 1)]; dst = kn; drow = r2;
  }
  const int c0 = lane * 4;
  const float4 e = *(const float4*)(emb + (long)idx * 256 + c0);
  const float4 u = *(const float4*)(ut + ((long)bb * NS_ + idx) * 256 + c0);
  float x0 = e.x + u.x, x1 = e.y + u.y, x2 = e.z + u.z, x3 = e.w + u.w;
  float s1 = x0 + x1 + x2 + x3;
  float s2 = x0 * x0 + x1 * x1 + x2 * x2 + x3 * x3;
#pragma unroll
  for (int off = 1; off < 64; off <<= 1) {
    s1 += __shfl_xor(s1, off);
    s2 += __shfl_xor(s2, off);
  }
  const float mean = s1 * (1.f / 256.f);
  const float inv = rsqrtf(s2 * (1.f / 256.f) - mean * mean + 1e-5f);
  const float4 scv = *(const float4*)(sc + c0);
  const float4 biv = *(const float4*)(bi + c0);
  ushort4 o;
  o.x = f2bf((x0 - mean) * inv * scv.x + biv.x);
  o.y = f2bf((x1 - mean) * inv * scv.y + biv.y);
  o.z = f2bf((x2 - mean) * inv * scv.z + biv.z);
  o.w = f2bf((x3 - mean) * inv * scv.w + biv.w);
  *(ushort4*)(dst + drow * 256 + c0) = o;
}

// ---------------- bf16 GEMM body: C[128 rows @m0, 128 cols @n0] ----------------
// EPI: 0 = store bf16,
//      4 = store bf16 TRANSPOSED per head -> Vt[b,h,dh,kv],
//      5 = store bf16 scaled by SCALE_ (attention Q pre-scale; 2^-3 is exact)
template <int EPI>
__device__ __forceinline__ void gemm_body(
    const ushort_t* __restrict__ A, const ushort_t* __restrict__ Bt,
    void* __restrict__ Cout, long m0, int n0, ushort_t* lAB) {
  ushort_t* lA = lAB;
  ushort_t* lB = lAB + 8192;
  const int tid = threadIdx.x;
  const int lane = tid & 63, w = tid >> 6;
  const int quad = lane >> 4, l16 = lane & 15;
  const int wm = w & 1, wn = w >> 1;

  f32x4 acc[4][4] = {};

  for (int kt = 0; kt < 4; ++kt) {
    const int k0 = kt * 64;
#pragma unroll
    for (int p = 0; p < 4; ++p) {
      const int ob = p * 4096 + tid * 16;  // byte offset in tile
      const int row = ob >> 7;             // 128B per row
      const int chunk = ((ob >> 4) & 7) ^ (row & 7);
      gld16(A + (m0 + row) * 256 + k0 + chunk * 8, (char*)lA + p * 4096 + w * 1024);
      gld16(Bt + (long)(n0 + row) * 256 + k0 + chunk * 8, (char*)lB + p * 4096 + w * 1024);
    }
    __syncthreads();
#pragma unroll
    for (int ki = 0; ki < 2; ++ki) {
      bf16x8 af[4], bfr[4];
#pragma unroll
      for (int i = 0; i < 4; ++i) {
        const int ra = wm * 64 + i * 16 + l16;
        const int ca = (ki * 4 + quad) ^ (ra & 7);
        af[i] = *(const bf16x8*)&lA[ra * 64 + ca * 8];
        const int rb = wn * 64 + i * 16 + l16;
        const int cb = (ki * 4 + quad) ^ (rb & 7);
        bfr[i] = *(const bf16x8*)&lB[rb * 64 + cb * 8];
      }
#pragma unroll
      for (int mi = 0; mi < 4; ++mi)
#pragma unroll
        for (int ni = 0; ni < 4; ++ni)
          acc[mi][ni] = __builtin_amdgcn_mfma_f32_16x16x32_bf16(af[mi], bfr[ni], acc[mi][ni], 0, 0, 0);
    }
    __syncthreads();
  }

  if (EPI == 4) {
    // transpose epilogue: this block covers kv-rows [m0, m0+128) of batch b = m0>>10
    // and cols (heads by*2, by*2+1). Write Vt[((b*4+h)*64+dh)*1024 + kv].
    const long b = m0 >> 10;
    const int kvseg = (int)(m0 & 1023);
#pragma unroll
    for (int hg = 0; hg < 2; ++hg) {
      if (wn == hg) {
#pragma unroll
        for (int mi = 0; mi < 4; ++mi)
#pragma unroll
          for (int ni = 0; ni < 4; ++ni)
#pragma unroll
            for (int r = 0; r < 4; ++r) {
              const int dh = ni * 16 + l16;                 // 0..63
              const int kvl = wm * 64 + mi * 16 + quad * 4 + r;  // 0..127
              lAB[dh * 128 + (((kvl >> 3) ^ (dh & 15)) << 3) + (kvl & 7)] =
                  f2bf(acc[mi][ni][r]);
            }
      }
      __syncthreads();
      {
        const int dh = tid >> 2;
        const int head = (n0 >> 6) + hg;
        ushort_t* dst = (ushort_t*)Cout +
            ((b * 4 + head) * 64 + dh) * 1024 + kvseg;
#pragma unroll
        for (int i = 0; i < 4; ++i) {
          const int c = (tid & 3) * 4 + i;
          const int cs = c ^ (dh & 15);
          *(uint4*)(dst + c * 8) = *(const uint4*)&lAB[dh * 128 + cs * 8];
        }
      }
      __syncthreads();
    }
    return;
  }

#pragma unroll
  for (int mi = 0; mi < 4; ++mi) {
#pragma unroll
    for (int ni = 0; ni < 4; ++ni) {
#pragma unroll
      for (int r = 0; r < 4; ++r) {
        const long row = m0 + wm * 64 + mi * 16 + quad * 4 + r;
        const int col = n0 + wn * 64 + ni * 16 + l16;
        float v = acc[mi][ni][r];
        if (EPI == 5) v *= SCALE_;
        ((ushort_t*)Cout)[row * 256 + col] = f2bf(v);
      }
    }
  }
}

// batched QKV: 0..255 -> Q@Wq (pre-scaled), 256..767 -> K@Wk, 768..1279 -> V@Wv (transposed out)
__global__ __launch_bounds__(256) void gemm_qkv(
    const ushort_t* __restrict__ qn, const ushort_t* __restrict__ kn,
    const ushort_t* __restrict__ wt,
    ushort_t* __restrict__ Qb, ushort_t* __restrict__ Kb, ushort_t* __restrict__ Vt) {
  __shared__ ushort_t lAB[16384];
  int idx = blockIdx.x;
  if (idx < 256) {
    gemm_body<5>(qn, wt, Qb, (long)(idx & 127) * 128, (idx >> 7) * 128, lAB);
  } else if (idx < 768) {
    idx -= 256;
    gemm_body<0>(kn, wt + 65536, Kb, (long)(idx & 255) * 128, (idx >> 8) * 128, lAB);
  } else {
    idx -= 768;
    gemm_body<4>(kn, wt + 131072, Vt, (long)(idx & 255) * 128, (idx >> 8) * 128, lAB);
  }
}

// ---------------- band GEMM: 64 rows x 256 cols per block, K=256 ----------------
// Wave w owns COLUMN BAND [w*64, w*64+64), acc[4][4]. Grid = 256 blocks = 1 block/CU
// = 1 wave/SIMD, so barrier stalls are fully exposed -> T3/T4 pipeline:
//   BK=32 phases, TRIPLE-buffered LDS (62KB), stage(kt+2) issued at phase top,
//   counted `s_waitcnt vmcnt(N)` + raw s_barrier (no vmcnt(0) drain mid-loop).
// 64B-row tiles need swizzle c ^= (row>>1)&3 for 2-way (free) LDS banking.
// K accumulation order = 8 sequential K=32 steps, bitwise-identical to before.
// MODE 2: v = acc + bias, gelu, store bf16            (W1 stage)
// MODE 6: inner LN over acc -> store f32 + bf16       (Wo stage)
// MODE 7: acc + bias + hf residual, outer LN, eff LN, atomic scatter to ut/out
template <int MODE>
__global__ __launch_bounds__(256) void gemm_band(
    const ushort_t* __restrict__ A, const ushort_t* __restrict__ Bt,
    const float* __restrict__ bias,
    const float* __restrict__ ln1s, const float* __restrict__ ln1b,
    const float* __restrict__ ln2s, const float* __restrict__ ln2b,
    const float* __restrict__ hfres, const int* __restrict__ qidx,
    float* __restrict__ outF, ushort_t* __restrict__ outB,
    float* __restrict__ ut, float* __restrict__ out) {
  __shared__ ushort_t lA[3][2048];   // 64r x 32k per buf (4KB), swizzled
  __shared__ ushort_t lB[3][8192];   // 256r x 32k per buf (16KB), swizzled
  __shared__ float sS1[64][4], sS2[64][4];  // per-row per-wave partials
  const int tid = threadIdx.x;
  const int lane = tid & 63, w = tid >> 6;
  const int quad = lane >> 4, l16 = lane & 15;
  const long m0 = (long)blockIdx.x * 64;

  // stage phase kt into buffer bu: 1 A pass + 4 B passes = 5 gld16/thread
  auto stage = [&](int kt, int bu) {
    const int k0 = kt * 32;
    {
      const int ob = tid * 16;
      const int row = ob >> 6;                 // 64B per row
      const int c = (ob >> 4) & 3;
      gld16(A + (m0 + row) * 256 + k0 + (c ^ ((row >> 1) & 3)) * 8,
            (char*)&lA[bu][0] + w * 1024);
    }
#pragma unroll
    for (int p = 0; p < 4; ++p) {
      const int ob = p * 4096 + tid * 16;
      const int row = ob >> 6;
      const int c = (ob >> 4) & 3;
      gld16(Bt + (long)row * 256 + k0 + (c ^ ((row >> 1) & 3)) * 8,
            (char*)&lB[bu][0] + p * 4096 + w * 1024);
    }
  };

  f32x4 acc[4][4] = {};
  stage(0, 0);
  stage(1, 1);
#pragma unroll
  for (int kt = 0; kt < 8; ++kt) {
    const int bu = kt % 3;
    if (kt < 6) stage(kt + 2, (kt + 2) % 3);
    // counted waits: retire stage(kt); keep up to 2 stages in flight
    if (kt < 6)       asm volatile("s_waitcnt vmcnt(10)" ::: "memory");
    else if (kt == 6) asm volatile("s_waitcnt vmcnt(5)" ::: "memory");
    else              asm volatile("s_waitcnt vmcnt(0)" ::: "memory");
    __builtin_amdgcn_s_barrier();          // RAW: buf[bu] visible to all waves
    __builtin_amdgcn_sched_barrier(0);
    bf16x8 af[4], bfr[4];
#pragma unroll
    for (int i = 0; i < 4; ++i) {
      const int ra = i * 16 + l16;
      af[i] = *(const bf16x8*)&lA[bu][ra * 32 + ((quad ^ ((ra >> 1) & 3)) * 8)];
      const int rb = w * 64 + i * 16 + l16;
      bfr[i] = *(const bf16x8*)&lB[bu][rb * 32 + ((quad ^ ((rb >> 1) & 3)) * 8)];
    }
#pragma unroll
    for (int mi = 0; mi < 4; ++mi)
#pragma unroll
      for (int ni = 0; ni < 4; ++ni)
        acc[mi][ni] = __builtin_amdgcn_mfma_f32_16x16x32_bf16(af[mi], bfr[ni], acc[mi][ni], 0, 0, 0);
    __builtin_amdgcn_sched_barrier(0);
    __builtin_amdgcn_s_barrier();          // WAR: all reads of buf[bu] done
  }

  // ---- epilogues. Lane holds rows (mi*16+quad*4+r) x cols (w*64+ni*16+l16). ----
  if (MODE == 2) {
    float bcol[4];
#pragma unroll
    for (int ni = 0; ni < 4; ++ni) bcol[ni] = bias[w * 64 + ni * 16 + l16];
#pragma unroll
    for (int mi = 0; mi < 4; ++mi)
#pragma unroll
      for (int r = 0; r < 4; ++r) {
        const long row = m0 + mi * 16 + quad * 4 + r;
#pragma unroll
        for (int ni = 0; ni < 4; ++ni) {
          float v = acc[mi][ni][r] + bcol[ni];
          const float u = 0.7978845608028654f * (v + 0.044715f * v * v * v);
          v = 0.5f * v * (1.0f + tanhf(u));
          outB[row * 256 + (w * 64 + ni * 16 + l16)] = f2bf(v);
        }
      }
    return;
  }

  if (MODE == 6) {
    // row partials over raw acc
#pragma unroll
    for (int mi = 0; mi < 4; ++mi)
#pragma unroll
      for (int r = 0; r < 4; ++r) {
        float a1 = 0.f, a2 = 0.f;
#pragma unroll
        for (int ni = 0; ni < 4; ++ni) {
          const float v = acc[mi][ni][r];
          a1 += v; a2 += v * v;
        }
#pragma unroll
        for (int off = 1; off < 16; off <<= 1) {
          a1 += __shfl_xor(a1, off);
          a2 += __shfl_xor(a2, off);
        }
        if (l16 == 0) {
          sS1[mi * 16 + quad * 4 + r][w] = a1;
          sS2[mi * 16 + quad * 4 + r][w] = a2;
        }
      }
    __syncthreads();
    float l1sv[4], l1bv[4];
#pragma unroll
    for (int ni = 0; ni < 4; ++ni) {
      const int col = w * 64 + ni * 16 + l16;
      l1sv[ni] = ln1s[col]; l1bv[ni] = ln1b[col];
    }
#pragma unroll
    for (int mi = 0; mi < 4; ++mi)
#pragma unroll
      for (int r = 0; r < 4; ++r) {
        const int rowi = mi * 16 + quad * 4 + r;
        const f32x4 v1 = *(const f32x4*)&sS1[rowi][0];
        const f32x4 v2 = *(const f32x4*)&sS2[rowi][0];
        const float s1 = v1[0] + v1[1] + v1[2] + v1[3];
        const float s2 = v2[0] + v2[1] + v2[2] + v2[3];
        const float mean = s1 * (1.f / 256.f);
        const float inv = rsqrtf(s2 * (1.f / 256.f) - mean * mean + 1e-5f);
        const long row = m0 + rowi;
#pragma unroll
        for (int ni = 0; ni < 4; ++ni) {
          const int col = w * 64 + ni * 16 + l16;
          const float y = (acc[mi][ni][r] - mean) * inv * l1sv[ni] + l1bv[ni];
          outF[row * 256 + col] = y;
          outB[row * 256 + col] = f2bf(y);
        }
      }
    return;
  }

  // MODE 7
  {
    float bcol[4], l1sv[4], l1bv[4], l2sv[4], l2bv[4];
#pragma unroll
    for (int ni = 0; ni < 4; ++ni) {
      const int col = w * 64 + ni * 16 + l16;
      bcol[ni] = bias[col];
      l1sv[ni] = ln1s[col]; l1bv[ni] = ln1b[col];
      l2sv[ni] = ln2s[col]; l2bv[ni] = ln2b[col];
    }
    // round 1: x = acc + bias + residual (in place), partials over x
#pragma unroll
    for (int mi = 0; mi < 4; ++mi)
#pragma unroll
      for (int r = 0; r < 4; ++r) {
        const long row = m0 + mi * 16 + quad * 4 + r;
        float a1 = 0.f, a2 = 0.f;
#pragma unroll
        for (int ni = 0; ni < 4; ++ni) {
          const int col = w * 64 + ni * 16 + l16;
          const float v = acc[mi][ni][r] + bcol[ni] + hfres[row * 256 + col];
          acc[mi][ni][r] = v;
          a1 += v; a2 += v * v;
        }
#pragma unroll
        for (int off = 1; off < 16; off <<= 1) {
          a1 += __shfl_xor(a1, off);
          a2 += __shfl_xor(a2, off);
        }
        if (l16 == 0) {
          sS1[mi * 16 + quad * 4 + r][w] = a1;
          sS2[mi * 16 + quad * 4 + r][w] = a2;
        }
      }
    __syncthreads();
    // apply outer LN -> y (in place); keep per-lane y partials in registers
    float py1[4][4], py2[4][4];
#pragma unroll
    for (int mi = 0; mi < 4; ++mi)
#pragma unroll
      for (int r = 0; r < 4; ++r) {
        const int rowi = mi * 16 + quad * 4 + r;
        const f32x4 v1 = *(const f32x4*)&sS1[rowi][0];
        const f32x4 v2 = *(const f32x4*)&sS2[rowi][0];
        const float s1 = v1[0] + v1[1] + v1[2] + v1[3];
        const float s2 = v2[0] + v2[1] + v2[2] + v2[3];
        const float mean = s1 * (1.f / 256.f);
        const float inv = rsqrtf(s2 * (1.f / 256.f) - mean * mean + 1e-5f);
        float a1 = 0.f, a2 = 0.f;
#pragma unroll
        for (int ni = 0; ni < 4; ++ni) {
          const float y = (acc[mi][ni][r] - mean) * inv * l1sv[ni] + l1bv[ni];
          acc[mi][ni][r] = y;
          a1 += y; a2 += y * y;
        }
        py1[mi][r] = a1; py2[mi][r] = a2;
      }
    __syncthreads();  // WAR: all round-1 reads of sS done before rewrite
    // round 2: partials over y
#pragma unroll
    for (int mi = 0; mi < 4; ++mi)
#pragma unroll
      for (int r = 0; r < 4; ++r) {
        float a1 = py1[mi][r], a2 = py2[mi][r];
#pragma unroll
        for (int off = 1; off < 16; off <<= 1) {
          a1 += __shfl_xor(a1, off);
          a2 += __shfl_xor(a2, off);
        }
        if (l16 == 0) {
          sS1[mi * 16 + quad * 4 + r][w] = a1;
          sS2[mi * 16 + quad * 4 + r][w] = a2;
        }
      }
    __syncthreads();
    // eff LN + scatter
#pragma unroll
    for (int mi = 0; mi < 4; ++mi)
#pragma unroll
      for (int r = 0; r < 4; ++r) {
        const int rowi = mi * 16 + quad * 4 + r;
        const f32x4 v1 = *(const f32x4*)&sS1[rowi][0];
        const f32x4 v2 = *(const f32x4*)&sS2[rowi][0];
        const float s1 = v1[0] + v1[1] + v1[2] + v1[3];
        const float s2 = v2[0] + v2[1] + v2[2] + v2[3];
        const float mean = s1 * (1.f / 256.f);
        const float inv = rsqrtf(s2 * (1.f / 256.f) - mean * mean + 1e-5f);
        const long row = m0 + rowi;
        const int idx = qidx[(int)(row & (NQ_ - 1))];
        const long base = ((row >> 9) * (long)NS_ + idx) * 256;
#pragma unroll
        for (int ni = 0; ni < 4; ++ni) {
          const int col = w * 64 + ni * 16 + l16;
          const float z = (acc[mi][ni][r] - mean) * inv * l2sv[ni] + l2bv[ni];
          atomicAdd(&ut[base + col], z);
          atomicAdd(&out[base + col], z);
        }
      }
  }
}

// ---------------- flash attention: per (q-tile of 64, head, batch) ----------------
// block id: bid = qt*128 + (b*4+h)  -> all 8 q-tiles of a (b,h) share bid%8 (same XCD)
//
// No-max softmax (verified R1-R5); l row-sums via mfma(P, ones).
// T3/T4 pipeline (pattern verified in gemm_band, R5): TRIPLE-buffered K/Vt
// (3x16KB), stageKV(kt+2) issued at phase top, counted vmcnt + raw s_barrier --
// loads get ~2 full compute phases to fly instead of ~8 MFMAs.
// Mask bits staged ONCE into LDS (lM, 8KB) so per-kt mask reads are DS ops and
// the vmcnt ledger stays exact: prologue 12 ops (Q2+M2+st0:4+st1:4); steady state
// issue 4 -> 12 in flight -> vmcnt(8) retires stage(kt); tail vmcnt(4)/vmcnt(0).
// WAR safety: stage(kt+2) overwrites buf[(kt-1)%3], issued only after the end
// barrier of kt-1 which all waves' reads precede (same proof as gemm_band).
// LDS 72KB -> 2 blocks/CU (was 4): TLP traded for 2-deep ILP.
__global__ __launch_bounds__(256) void attn_kernel(
    const ushort_t* __restrict__ Qb, const ushort_t* __restrict__ Kb,
    const ushort_t* __restrict__ Vt, const u64_t* __restrict__ mbits,
    ushort_t* __restrict__ ctx) {
  __shared__ ushort_t lQ[4096];
  __shared__ ushort_t lK[3][4096];
  __shared__ ushort_t lVt[3][4096];
  __shared__ ushort_t lP[4096];
  __shared__ u64_t lM[1024];   // [row 0..63][word 0..15]
  const int tid = threadIdx.x;
  const int lane = tid & 63, w = tid >> 6;
  const int quad = lane >> 4, l16 = lane & 15;
  const int bid = blockIdx.x;
  const int qt = bid >> 7, pair = bid & 127;
  const int h = pair & 3, b = pair >> 2;
  const int q0 = qt * 64;
  const long qrow0 = (long)b * NQ_ + q0;
  const long krow0 = (long)b * NK_;
  const ushort_t* vbase = Vt + ((long)pair * 64) * 1024;  // [dh][kv] for this (b,h)

  // prologue: stage Q (2 passes, swizzled) + mask words (2 passes, linear copy)
#pragma unroll
  for (int p = 0; p < 2; ++p) {
    const int ob = p * 4096 + tid * 16;
    const int row = ob >> 7;
    const int chunk = ((ob >> 4) & 7) ^ (row & 7);
    gld16(Qb + (qrow0 + row) * 256 + h * 64 + chunk * 8, (char*)lQ + p * 4096 + w * 1024);
    gld16((const char*)(mbits + (long)q0 * 16) + ob, (char*)lM + p * 4096 + w * 1024);
  }

  auto stageKV = [&](int kt, int bu) {
#pragma unroll
    for (int p = 0; p < 2; ++p) {
      const int ob = p * 4096 + tid * 16;
      const int row = ob >> 7;
      const int chunk = ((ob >> 4) & 7) ^ (row & 7);
      gld16(Kb + (krow0 + kt * 64 + row) * 256 + h * 64 + chunk * 8,
            (char*)&lK[bu][0] + p * 4096 + w * 1024);
      gld16(vbase + (long)row * 1024 + kt * 64 + chunk * 8,
            (char*)&lVt[bu][0] + p * 4096 + w * 1024);
    }
  };

  f32x4 o_acc[4] = {};
  f32x4 l_acc = {};
  bf16x8 ones;
#pragma unroll
  for (int i = 0; i < 8; ++i) ones[i] = (__bf16)1.0f;

  stageKV(0, 0);
  stageKV(1, 1);

  for (int kt = 0; kt < 16; ++kt) {
    const int bu = kt % 3;
    if (kt < 14) stageKV(kt + 2, (kt + 2) % 3);
    // retire stage(kt) (+Q/lM on kt=0); keep 2 stages (8 ops) in flight
    if (kt < 14)       asm volatile("s_waitcnt vmcnt(8)" ::: "memory");
    else if (kt == 14) asm volatile("s_waitcnt vmcnt(4)" ::: "memory");
    else               asm volatile("s_waitcnt vmcnt(0)" ::: "memory");
    __builtin_amdgcn_s_barrier();        // RAW: buf[bu] (+lQ/lM first iter) ready
    __builtin_amdgcn_sched_barrier(0);

    // mask words for this kt (DS reads; lgkmcnt-counted, vmcnt untouched)
    u64_t wd[4];
#pragma unroll
    for (int r = 0; r < 4; ++r) wd[r] = lM[(w * 16 + quad * 4 + r) * 16 + kt];

    // S = Q K^T  (wave handles 16 q-rows x 64 keys); Q already carries SCALE
    f32x4 s[4] = {};
    __builtin_amdgcn_s_setprio(1);
#pragma unroll
    for (int ki = 0; ki < 2; ++ki) {
      const int rq = w * 16 + l16;
      const int cq = (ki * 4 + quad) ^ (rq & 7);
      const bf16x8 qf = *(const bf16x8*)&lQ[rq * 64 + cq * 8];
#pragma unroll
      for (int ni = 0; ni < 4; ++ni) {
        const int rk = ni * 16 + l16;
        const int ck = (ki * 4 + quad) ^ (rk & 7);
        const bf16x8 kf = *(const bf16x8*)&lK[bu][rk * 64 + ck * 8];
        s[ni] = __builtin_amdgcn_mfma_f32_16x16x32_bf16(qf, kf, s[ni], 0, 0, 0);
      }
    }
    __builtin_amdgcn_s_setprio(0);

    // P = keep ? exp(S) : 0 ; write P to LDS (swizzled A-layout, wave-private rows)
#pragma unroll
    for (int r = 0; r < 4; ++r) {
      const int rowp = w * 16 + quad * 4 + r;
#pragma unroll
      for (int ni = 0; ni < 4; ++ni) {
        const bool keep = (wd[r] >> (ni * 16 + l16)) & 1ull;
        const float pv = keep ? __expf(s[ni][r]) : 0.f;
        const int col = ni * 16 + l16;
        lP[rowp * 64 + (((col >> 3) ^ (rowp & 7)) << 3) + (col & 7)] = f2bf(pv);
      }
    }

    // O += P V ; l += P . 1  (row sums via matrix pipe)
    __builtin_amdgcn_s_setprio(1);
#pragma unroll
    for (int ki = 0; ki < 2; ++ki) {
      const int rp = w * 16 + l16;
      const int cp = (ki * 4 + quad) ^ (rp & 7);
      const bf16x8 pf = *(const bf16x8*)&lP[rp * 64 + cp * 8];
      l_acc = __builtin_amdgcn_mfma_f32_16x16x32_bf16(pf, ones, l_acc, 0, 0, 0);
#pragma unroll
      for (int ni = 0; ni < 4; ++ni) {
        const int rv = ni * 16 + l16;
        const int cv = (ki * 4 + quad) ^ (rv & 7);
        const bf16x8 vf = *(const bf16x8*)&lVt[bu][rv * 64 + cv * 8];
        o_acc[ni] = __builtin_amdgcn_mfma_f32_16x16x32_bf16(pf, vf, o_acc[ni], 0, 0, 0);
      }
    }
    __builtin_amdgcn_s_setprio(0);
    __builtin_amdgcn_sched_barrier(0);
    __builtin_amdgcn_s_barrier();        // WAR: all reads of buf[bu] done
  }

  // normalize + write ctx (bf16)
#pragma unroll
  for (int r = 0; r < 4; ++r) {
    const float inv = 1.0f / l_acc[r];
    const long rowg = qrow0 + w * 16 + quad * 4 + r;
#pragma unroll
    for (int ni = 0; ni < 4; ++ni) {
      const int col = h * 64 + ni * 16 + l16;
      ctx[rowg * 256 + col] = f2bf(o_acc[ni][r] * inv);
    }
  }
}

extern "C" void kernel_launch(void* const* d_in, const int* in_sizes, int n_in,
                              void* d_out, int out_size, void* d_ws, size_t ws_size,
                              hipStream_t stream) {
  float* ut = (float*)d_in[0];  // mutated in place; harness restores before every launch
  const float* emb = (const float*)d_in[1];
  const float* maskl = (const float*)d_in[2];
  const float* Wq = (const float*)d_in[3];
  const float* Wk = (const float*)d_in[4];
  const float* Wv = (const float*)d_in[5];
  const float* Wo = (const float*)d_in[6];
  const float* W1 = (const float*)d_in[7];
  const float* b1 = (const float*)d_in[8];
  const float* W2 = (const float*)d_in[9];
  const float* b2 = (const float*)d_in[10];
  const float* sys_s = (const float*)d_in[11];
  const float* sys_b = (const float*)d_in[12];
  const float* eff_s = (const float*)d_in[13];
  const float* eff_b = (const float*)d_in[14];
  const float* in_s = (const float*)d_in[15];
  const float* in_b = (const float*)d_in[16];
  const float* out_s = (const float*)d_in[17];
  const float* out_b = (const float*)d_in[18];
  const int* qidx = (const int*)d_in[19];
  const int* kidx = (const int*)d_in[20];
  float* out = (float*)d_out;

  char* p = (char*)d_ws;
  auto carve = [&](size_t bytes) {
    void* r = (void*)p;
    p += (bytes + 255) & ~(size_t)255;
    return r;
  };
  ushort_t* wt = (ushort_t*)carve((size_t)6 * 65536 * 2);
  u64_t* mb = (u64_t*)carve((size_t)L_ * NQ_ * (NK_ / 64) * 8);
  ushort_t* qn = (ushort_t*)carve((size_t)16384 * 256 * 2);  // reused as ctx
  ushort_t* kn = (ushort_t*)carve((size_t)32768 * 256 * 2);
  ushort_t* Qb = (ushort_t*)carve((size_t)16384 * 256 * 2);  // reused as g
  ushort_t* Kb = (ushort_t*)carve((size_t)32768 * 256 * 2);  // reused as hb
  ushort_t* Vt = (ushort_t*)carve((size_t)32768 * 256 * 2);  // reused as hf (f32)

  ushort_t* ctx = qn;
  ushort_t* g = Qb;
  ushort_t* hb = Kb;
  float* hf = (float*)Vt;

  hipMemsetAsync(d_out, 0, (size_t)out_size, stream);
  prep_w<<<1536, 256, 0, stream>>>(Wq, Wk, Wv, Wo, W1, W2, wt);
  prep_mask<<<(L_ * NQ_ * NK_) / 256, 256, 0, stream>>>(maskl, mb);

  for (int l = 0; l < L_; ++l) {
    gather_ln<<<B_ * (NQ_ + NK_) / 4, 256, 0, stream>>>(
        ut, emb, qidx + l * NQ_, kidx + l * NK_, sys_s, sys_b, qn, kn);
    gemm_qkv<<<1280, 256, 0, stream>>>(qn, kn, wt, Qb, Kb, Vt);
    attn_kernel<<<1024, 256, 0, stream>>>(
        Qb, Kb, Vt, mb + (size_t)l * NQ_ * (NK_ / 64), ctx);
    // Wo + inner LN fused
    gemm_band<6><<<256, 256, 0, stream>>>(
        ctx, wt + 3 * 65536, nullptr, in_s, in_b, nullptr, nullptr,
        nullptr, nullptr, hf, hb, nullptr, nullptr);
    // W1 + bias + gelu
    gemm_band<2><<<256, 256, 0, stream>>>(
        hb, wt + 4 * 65536, b1, nullptr, nullptr, nullptr, nullptr,
        nullptr, nullptr, nullptr, g, nullptr, nullptr);
    // W2 + bias + residual + outer LN + eff LN + scatter fused
    gemm_band<7><<<256, 256, 0, stream>>>(
        g, wt + 5 * 65536, b2, out_s, out_b, eff_s, eff_b,
        hf, qidx + l * NQ_, nullptr, nullptr, ut, out);
  }
}

// Round 7
// 1231.016 us; speedup vs baseline: 1.4199x; 1.4199x over previous
//
#include <hip/hip_runtime.h>
#include <cstdint>
#include <cstddef>

#define B_ 32
#define NS_ 4096
#define D_ 256
#define H_ 4
#define L_ 6
#define NQ_ 512
#define NK_ 1024
#define DH_ 64
#define SCALE_ 0.125f

typedef unsigned short ushort_t;
typedef unsigned long long u64_t;
typedef __bf16 bf16x8 __attribute__((ext_vector_type(8)));
typedef float f32x4 __attribute__((ext_vector_type(4)));

__device__ __forceinline__ ushort_t f2bf(float f) {
  unsigned u = __float_as_uint(f);
  u += 0x7fffu + ((u >> 16) & 1u);
  return (ushort_t)(u >> 16);
}

// async global->LDS, 16B per lane. lds ptr must be wave-uniform (HW adds lane*16).
__device__ __forceinline__ void gld16(const void* g, void* l) {
  __builtin_amdgcn_global_load_lds(
      (__attribute__((address_space(1))) void*)(uintptr_t)g,
      (__attribute__((address_space(3))) void*)(uintptr_t)l, 16, 0, 0);
}

// ---------------- weight prep: Wt[n][k] = bf16(W[k][n]) ----------------
__global__ __launch_bounds__(256) void prep_w(
    const float* __restrict__ w0, const float* __restrict__ w1,
    const float* __restrict__ w2, const float* __restrict__ w3,
    const float* __restrict__ w4, const float* __restrict__ w5,
    ushort_t* __restrict__ wt) {
  const int sel = blockIdx.x >> 8;
  const int n = blockIdx.x & 255;
  const int k = threadIdx.x;
  const float* W = sel == 0 ? w0 : sel == 1 ? w1 : sel == 2 ? w2
                 : sel == 3 ? w3 : sel == 4 ? w4 : w5;
  wt[sel * 65536 + n * 256 + k] = f2bf(W[k * 256 + n]);
}

// ---------------- mask prep: pack (maskl > 0.5) into bits, 1 u64 per 64 cols ----
__global__ __launch_bounds__(256) void prep_mask(
    const float* __restrict__ ml, u64_t* __restrict__ mb) {
  const long gid = (long)blockIdx.x * 256 + threadIdx.x;  // over L*NQ*NK
  const bool m = ml[gid] > 0.5f;
  const u64_t bal = __ballot(m);
  if ((threadIdx.x & 63) == 0) mb[gid >> 6] = bal;
}

// ---------------- mask repack: pm[(l*NQ+q)*16 + l16] bit(kt*4+ni) =
//                  mb[(l*NQ+q)*16 + kt] bit(ni*16+l16) ----------------
// Lets each attn thread keep ALL its mask bits (16 kt x 4 ni, for 4 rows) in
// 4 u64 registers loaded once -- mask never touches LDS or the vmcnt ledger.
__global__ __launch_bounds__(256) void prep_mask2(
    const u64_t* __restrict__ mb, u64_t* __restrict__ pm) {
  const long gid = (long)blockIdx.x * 256 + threadIdx.x;  // over L*NQ*16
  const long rowbase = (gid >> 4) << 4;
  const int l16 = (int)(gid & 15);
  u64_t v = 0;
#pragma unroll
  for (int kt = 0; kt < 16; ++kt) {
    const u64_t wsrc = mb[rowbase + kt];
#pragma unroll
    for (int ni = 0; ni < 4; ++ni)
      v |= ((wsrc >> (ni * 16 + l16)) & 1ull) << (kt * 4 + ni);
  }
  pm[gid] = v;
}

// ---------------- gather + sys LayerNorm -> bf16 (one WAVE per row) ----------------
// lane loads float4 (cols lane*4..+3); 6-step shfl_xor reduce; no LDS, no barriers.
__global__ __launch_bounds__(256) void gather_ln(
    const float* __restrict__ ut, const float* __restrict__ emb,
    const int* __restrict__ qidx, const int* __restrict__ kidx,
    const float* __restrict__ sc, const float* __restrict__ bi,
    ushort_t* __restrict__ qn, ushort_t* __restrict__ kn) {
  const int w = threadIdx.x >> 6, lane = threadIdx.x & 63;
  const int R = blockIdx.x * 4 + w;
  int bb, idx;
  ushort_t* dst;
  long drow;
  if (R < B_ * NQ_) {
    bb = R >> 9; idx = qidx[R & (NQ_ - 1)]; dst = qn; drow = R;
  } else {
    const int r2 = R - B_ * NQ_;
    bb = r2 >> 10; idx = kidx[r2 & (NK_ - 1)]; dst = kn; drow = r2;
  }
  const int c0 = lane * 4;
  const float4 e = *(const float4*)(emb + (long)idx * 256 + c0);
  const float4 u = *(const float4*)(ut + ((long)bb * NS_ + idx) * 256 + c0);
  float x0 = e.x + u.x, x1 = e.y + u.y, x2 = e.z + u.z, x3 = e.w + u.w;
  float s1 = x0 + x1 + x2 + x3;
  float s2 = x0 * x0 + x1 * x1 + x2 * x2 + x3 * x3;
#pragma unroll
  for (int off = 1; off < 64; off <<= 1) {
    s1 += __shfl_xor(s1, off);
    s2 += __shfl_xor(s2, off);
  }
  const float mean = s1 * (1.f / 256.f);
  const float inv = rsqrtf(s2 * (1.f / 256.f) - mean * mean + 1e-5f);
  const float4 scv = *(const float4*)(sc + c0);
  const float4 biv = *(const float4*)(bi + c0);
  ushort4 o;
  o.x = f2bf((x0 - mean) * inv * scv.x + biv.x);
  o.y = f2bf((x1 - mean) * inv * scv.y + biv.y);
  o.z = f2bf((x2 - mean) * inv * scv.z + biv.z);
  o.w = f2bf((x3 - mean) * inv * scv.w + biv.w);
  *(ushort4*)(dst + drow * 256 + c0) = o;
}

// ---------------- bf16 GEMM body: C[128 rows @m0, 128 cols @n0] ----------------
// EPI: 0 = store bf16,
//      4 = store bf16 TRANSPOSED per head -> Vt[b,h,dh,kv],
//      5 = store bf16 scaled by SCALE_ (attention Q pre-scale; 2^-3 is exact)
template <int EPI>
__device__ __forceinline__ void gemm_body(
    const ushort_t* __restrict__ A, const ushort_t* __restrict__ Bt,
    void* __restrict__ Cout, long m0, int n0, ushort_t* lAB) {
  ushort_t* lA = lAB;
  ushort_t* lB = lAB + 8192;
  const int tid = threadIdx.x;
  const int lane = tid & 63, w = tid >> 6;
  const int quad = lane >> 4, l16 = lane & 15;
  const int wm = w & 1, wn = w >> 1;

  f32x4 acc[4][4] = {};

  for (int kt = 0; kt < 4; ++kt) {
    const int k0 = kt * 64;
#pragma unroll
    for (int p = 0; p < 4; ++p) {
      const int ob = p * 4096 + tid * 16;  // byte offset in tile
      const int row = ob >> 7;             // 128B per row
      const int chunk = ((ob >> 4) & 7) ^ (row & 7);
      gld16(A + (m0 + row) * 256 + k0 + chunk * 8, (char*)lA + p * 4096 + w * 1024);
      gld16(Bt + (long)(n0 + row) * 256 + k0 + chunk * 8, (char*)lB + p * 4096 + w * 1024);
    }
    __syncthreads();
#pragma unroll
    for (int ki = 0; ki < 2; ++ki) {
      bf16x8 af[4], bfr[4];
#pragma unroll
      for (int i = 0; i < 4; ++i) {
        const int ra = wm * 64 + i * 16 + l16;
        const int ca = (ki * 4 + quad) ^ (ra & 7);
        af[i] = *(const bf16x8*)&lA[ra * 64 + ca * 8];
        const int rb = wn * 64 + i * 16 + l16;
        const int cb = (ki * 4 + quad) ^ (rb & 7);
        bfr[i] = *(const bf16x8*)&lB[rb * 64 + cb * 8];
      }
#pragma unroll
      for (int mi = 0; mi < 4; ++mi)
#pragma unroll
        for (int ni = 0; ni < 4; ++ni)
          acc[mi][ni] = __builtin_amdgcn_mfma_f32_16x16x32_bf16(af[mi], bfr[ni], acc[mi][ni], 0, 0, 0);
    }
    __syncthreads();
  }

  if (EPI == 4) {
    // transpose epilogue: this block covers kv-rows [m0, m0+128) of batch b = m0>>10
    // and cols (heads by*2, by*2+1). Write Vt[((b*4+h)*64+dh)*1024 + kv].
    const long b = m0 >> 10;
    const int kvseg = (int)(m0 & 1023);
#pragma unroll
    for (int hg = 0; hg < 2; ++hg) {
      if (wn == hg) {
#pragma unroll
        for (int mi = 0; mi < 4; ++mi)
#pragma unroll
          for (int ni = 0; ni < 4; ++ni)
#pragma unroll
            for (int r = 0; r < 4; ++r) {
              const int dh = ni * 16 + l16;                 // 0..63
              const int kvl = wm * 64 + mi * 16 + quad * 4 + r;  // 0..127
              lAB[dh * 128 + (((kvl >> 3) ^ (dh & 15)) << 3) + (kvl & 7)] =
                  f2bf(acc[mi][ni][r]);
            }
      }
      __syncthreads();
      {
        const int dh = tid >> 2;
        const int head = (n0 >> 6) + hg;
        ushort_t* dst = (ushort_t*)Cout +
            ((b * 4 + head) * 64 + dh) * 1024 + kvseg;
#pragma unroll
        for (int i = 0; i < 4; ++i) {
          const int c = (tid & 3) * 4 + i;
          const int cs = c ^ (dh & 15);
          *(uint4*)(dst + c * 8) = *(const uint4*)&lAB[dh * 128 + cs * 8];
        }
      }
      __syncthreads();
    }
    return;
  }

#pragma unroll
  for (int mi = 0; mi < 4; ++mi) {
#pragma unroll
    for (int ni = 0; ni < 4; ++ni) {
#pragma unroll
      for (int r = 0; r < 4; ++r) {
        const long row = m0 + wm * 64 + mi * 16 + quad * 4 + r;
        const int col = n0 + wn * 64 + ni * 16 + l16;
        float v = acc[mi][ni][r];
        if (EPI == 5) v *= SCALE_;
        ((ushort_t*)Cout)[row * 256 + col] = f2bf(v);
      }
    }
  }
}

// batched QKV: 0..255 -> Q@Wq (pre-scaled), 256..767 -> K@Wk, 768..1279 -> V@Wv (transposed out)
__global__ __launch_bounds__(256) void gemm_qkv(
    const ushort_t* __restrict__ qn, const ushort_t* __restrict__ kn,
    const ushort_t* __restrict__ wt,
    ushort_t* __restrict__ Qb, ushort_t* __restrict__ Kb, ushort_t* __restrict__ Vt) {
  __shared__ ushort_t lAB[16384];
  int idx = blockIdx.x;
  if (idx < 256) {
    gemm_body<5>(qn, wt, Qb, (long)(idx & 127) * 128, (idx >> 7) * 128, lAB);
  } else if (idx < 768) {
    idx -= 256;
    gemm_body<0>(kn, wt + 65536, Kb, (long)(idx & 255) * 128, (idx >> 8) * 128, lAB);
  } else {
    idx -= 768;
    gemm_body<4>(kn, wt + 131072, Vt, (long)(idx & 255) * 128, (idx >> 8) * 128, lAB);
  }
}

// ---------------- band GEMM: 64 rows x 256 cols per block, K=256 ----------------
// (verified R5: T3/T4 pipeline, triple-buffered BK=32, counted vmcnt, 1563-class
// schedule at 1 block/CU). Unchanged from R5.
template <int MODE>
__global__ __launch_bounds__(256) void gemm_band(
    const ushort_t* __restrict__ A, const ushort_t* __restrict__ Bt,
    const float* __restrict__ bias,
    const float* __restrict__ ln1s, const float* __restrict__ ln1b,
    const float* __restrict__ ln2s, const float* __restrict__ ln2b,
    const float* __restrict__ hfres, const int* __restrict__ qidx,
    float* __restrict__ outF, ushort_t* __restrict__ outB,
    float* __restrict__ ut, float* __restrict__ out) {
  __shared__ ushort_t lA[3][2048];   // 64r x 32k per buf (4KB), swizzled
  __shared__ ushort_t lB[3][8192];   // 256r x 32k per buf (16KB), swizzled
  __shared__ float sS1[64][4], sS2[64][4];  // per-row per-wave partials
  const int tid = threadIdx.x;
  const int lane = tid & 63, w = tid >> 6;
  const int quad = lane >> 4, l16 = lane & 15;
  const long m0 = (long)blockIdx.x * 64;

  // stage phase kt into buffer bu: 1 A pass + 4 B passes = 5 gld16/thread
  auto stage = [&](int kt, int bu) {
    const int k0 = kt * 32;
    {
      const int ob = tid * 16;
      const int row = ob >> 6;                 // 64B per row
      const int c = (ob >> 4) & 3;
      gld16(A + (m0 + row) * 256 + k0 + (c ^ ((row >> 1) & 3)) * 8,
            (char*)&lA[bu][0] + w * 1024);
    }
#pragma unroll
    for (int p = 0; p < 4; ++p) {
      const int ob = p * 4096 + tid * 16;
      const int row = ob >> 6;
      const int c = (ob >> 4) & 3;
      gld16(Bt + (long)row * 256 + k0 + (c ^ ((row >> 1) & 3)) * 8,
            (char*)&lB[bu][0] + p * 4096 + w * 1024);
    }
  };

  f32x4 acc[4][4] = {};
  stage(0, 0);
  stage(1, 1);
#pragma unroll
  for (int kt = 0; kt < 8; ++kt) {
    const int bu = kt % 3;
    if (kt < 6) stage(kt + 2, (kt + 2) % 3);
    // counted waits: retire stage(kt); keep up to 2 stages in flight
    if (kt < 6)       asm volatile("s_waitcnt vmcnt(10)" ::: "memory");
    else if (kt == 6) asm volatile("s_waitcnt vmcnt(5)" ::: "memory");
    else              asm volatile("s_waitcnt vmcnt(0)" ::: "memory");
    __builtin_amdgcn_s_barrier();          // RAW: buf[bu] visible to all waves
    __builtin_amdgcn_sched_barrier(0);
    bf16x8 af[4], bfr[4];
#pragma unroll
    for (int i = 0; i < 4; ++i) {
      const int ra = i * 16 + l16;
      af[i] = *(const bf16x8*)&lA[bu][ra * 32 + ((quad ^ ((ra >> 1) & 3)) * 8)];
      const int rb = w * 64 + i * 16 + l16;
      bfr[i] = *(const bf16x8*)&lB[bu][rb * 32 + ((quad ^ ((rb >> 1) & 3)) * 8)];
    }
#pragma unroll
    for (int mi = 0; mi < 4; ++mi)
#pragma unroll
      for (int ni = 0; ni < 4; ++ni)
        acc[mi][ni] = __builtin_amdgcn_mfma_f32_16x16x32_bf16(af[mi], bfr[ni], acc[mi][ni], 0, 0, 0);
    __builtin_amdgcn_sched_barrier(0);
    __builtin_amdgcn_s_barrier();          // WAR: all reads of buf[bu] done
  }

  // ---- epilogues. Lane holds rows (mi*16+quad*4+r) x cols (w*64+ni*16+l16). ----
  if (MODE == 2) {
    float bcol[4];
#pragma unroll
    for (int ni = 0; ni < 4; ++ni) bcol[ni] = bias[w * 64 + ni * 16 + l16];
#pragma unroll
    for (int mi = 0; mi < 4; ++mi)
#pragma unroll
      for (int r = 0; r < 4; ++r) {
        const long row = m0 + mi * 16 + quad * 4 + r;
#pragma unroll
        for (int ni = 0; ni < 4; ++ni) {
          float v = acc[mi][ni][r] + bcol[ni];
          const float u = 0.7978845608028654f * (v + 0.044715f * v * v * v);
          v = 0.5f * v * (1.0f + tanhf(u));
          outB[row * 256 + (w * 64 + ni * 16 + l16)] = f2bf(v);
        }
      }
    return;
  }

  if (MODE == 6) {
    // row partials over raw acc
#pragma unroll
    for (int mi = 0; mi < 4; ++mi)
#pragma unroll
      for (int r = 0; r < 4; ++r) {
        float a1 = 0.f, a2 = 0.f;
#pragma unroll
        for (int ni = 0; ni < 4; ++ni) {
          const float v = acc[mi][ni][r];
          a1 += v; a2 += v * v;
        }
#pragma unroll
        for (int off = 1; off < 16; off <<= 1) {
          a1 += __shfl_xor(a1, off);
          a2 += __shfl_xor(a2, off);
        }
        if (l16 == 0) {
          sS1[mi * 16 + quad * 4 + r][w] = a1;
          sS2[mi * 16 + quad * 4 + r][w] = a2;
        }
      }
    __syncthreads();
    float l1sv[4], l1bv[4];
#pragma unroll
    for (int ni = 0; ni < 4; ++ni) {
      const int col = w * 64 + ni * 16 + l16;
      l1sv[ni] = ln1s[col]; l1bv[ni] = ln1b[col];
    }
#pragma unroll
    for (int mi = 0; mi < 4; ++mi)
#pragma unroll
      for (int r = 0; r < 4; ++r) {
        const int rowi = mi * 16 + quad * 4 + r;
        const f32x4 v1 = *(const f32x4*)&sS1[rowi][0];
        const f32x4 v2 = *(const f32x4*)&sS2[rowi][0];
        const float s1 = v1[0] + v1[1] + v1[2] + v1[3];
        const float s2 = v2[0] + v2[1] + v2[2] + v2[3];
        const float mean = s1 * (1.f / 256.f);
        const float inv = rsqrtf(s2 * (1.f / 256.f) - mean * mean + 1e-5f);
        const long row = m0 + rowi;
#pragma unroll
        for (int ni = 0; ni < 4; ++ni) {
          const int col = w * 64 + ni * 16 + l16;
          const float y = (acc[mi][ni][r] - mean) * inv * l1sv[ni] + l1bv[ni];
          outF[row * 256 + col] = y;
          outB[row * 256 + col] = f2bf(y);
        }
      }
    return;
  }

  // MODE 7
  {
    float bcol[4], l1sv[4], l1bv[4], l2sv[4], l2bv[4];
#pragma unroll
    for (int ni = 0; ni < 4; ++ni) {
      const int col = w * 64 + ni * 16 + l16;
      bcol[ni] = bias[col];
      l1sv[ni] = ln1s[col]; l1bv[ni] = ln1b[col];
      l2sv[ni] = ln2s[col]; l2bv[ni] = ln2b[col];
    }
    // round 1: x = acc + bias + residual (in place), partials over x
#pragma unroll
    for (int mi = 0; mi < 4; ++mi)
#pragma unroll
      for (int r = 0; r < 4; ++r) {
        const long row = m0 + mi * 16 + quad * 4 + r;
        float a1 = 0.f, a2 = 0.f;
#pragma unroll
        for (int ni = 0; ni < 4; ++ni) {
          const int col = w * 64 + ni * 16 + l16;
          const float v = acc[mi][ni][r] + bcol[ni] + hfres[row * 256 + col];
          acc[mi][ni][r] = v;
          a1 += v; a2 += v * v;
        }
#pragma unroll
        for (int off = 1; off < 16; off <<= 1) {
          a1 += __shfl_xor(a1, off);
          a2 += __shfl_xor(a2, off);
        }
        if (l16 == 0) {
          sS1[mi * 16 + quad * 4 + r][w] = a1;
          sS2[mi * 16 + quad * 4 + r][w] = a2;
        }
      }
    __syncthreads();
    // apply outer LN -> y (in place); keep per-lane y partials in registers
    float py1[4][4], py2[4][4];
#pragma unroll
    for (int mi = 0; mi < 4; ++mi)
#pragma unroll
      for (int r = 0; r < 4; ++r) {
        const int rowi = mi * 16 + quad * 4 + r;
        const f32x4 v1 = *(const f32x4*)&sS1[rowi][0];
        const f32x4 v2 = *(const f32x4*)&sS2[rowi][0];
        const float s1 = v1[0] + v1[1] + v1[2] + v1[3];
        const float s2 = v2[0] + v2[1] + v2[2] + v2[3];
        const float mean = s1 * (1.f / 256.f);
        const float inv = rsqrtf(s2 * (1.f / 256.f) - mean * mean + 1e-5f);
        float a1 = 0.f, a2 = 0.f;
#pragma unroll
        for (int ni = 0; ni < 4; ++ni) {
          const float y = (acc[mi][ni][r] - mean) * inv * l1sv[ni] + l1bv[ni];
          acc[mi][ni][r] = y;
          a1 += y; a2 += y * y;
        }
        py1[mi][r] = a1; py2[mi][r] = a2;
      }
    __syncthreads();  // WAR: all round-1 reads of sS done before rewrite
    // round 2: partials over y
#pragma unroll
    for (int mi = 0; mi < 4; ++mi)
#pragma unroll
      for (int r = 0; r < 4; ++r) {
        float a1 = py1[mi][r], a2 = py2[mi][r];
#pragma unroll
        for (int off = 1; off < 16; off <<= 1) {
          a1 += __shfl_xor(a1, off);
          a2 += __shfl_xor(a2, off);
        }
        if (l16 == 0) {
          sS1[mi * 16 + quad * 4 + r][w] = a1;
          sS2[mi * 16 + quad * 4 + r][w] = a2;
        }
      }
    __syncthreads();
    // eff LN + scatter
#pragma unroll
    for (int mi = 0; mi < 4; ++mi)
#pragma unroll
      for (int r = 0; r < 4; ++r) {
        const int rowi = mi * 16 + quad * 4 + r;
        const f32x4 v1 = *(const f32x4*)&sS1[rowi][0];
        const f32x4 v2 = *(const f32x4*)&sS2[rowi][0];
        const float s1 = v1[0] + v1[1] + v1[2] + v1[3];
        const float s2 = v2[0] + v2[1] + v2[2] + v2[3];
        const float mean = s1 * (1.f / 256.f);
        const float inv = rsqrtf(s2 * (1.f / 256.f) - mean * mean + 1e-5f);
        const long row = m0 + rowi;
        const int idx = qidx[(int)(row & (NQ_ - 1))];
        const long base = ((row >> 9) * (long)NS_ + idx) * 256;
#pragma unroll
        for (int ni = 0; ni < 4; ++ni) {
          const int col = w * 64 + ni * 16 + l16;
          const float z = (acc[mi][ni][r] - mean) * inv * l2sv[ni] + l2bv[ni];
          atomicAdd(&ut[base + col], z);
          atomicAdd(&out[base + col], z);
        }
      }
  }
}

// ---------------- flash attention: per (q-tile of 64, head, batch) ----------------
// block id: bid = qt*128 + (b*4+h)  -> all 8 q-tiles of a (b,h) share bid%8 (same XCD)
//
// No-max softmax (verified R1-R5); l row-sums via mfma(P, ones).
// R6 lesson: 72KB LDS dropped occupancy 4->2 blocks/CU and cost +487us. This
// version gets the counted-vmcnt pipeline at UNCHANGED 40KB/4-blocks-per-CU by
// removing LDS consumers instead of adding buffers:
//  - Q-hoist: each thread's 2 Q fragments are loop-invariant -> loaded once
//    from global straight to VGPRs (no lQ, no swizzle, -2 ds_read/phase).
//  - bit-transposed masks (prep_mask2): thread (quad,l16) holds all 16kt x 4ni
//    bits for its 4 rows in 4 u64 regs, loaded once (no lM, no per-phase loads).
//  - K/Vt double-buffered 2x16KB; lP 8KB -> 40KB total.
// vmcnt ledger (all per-phase VMEM is gld16): prologue {Q:2,pm:4 compiler-
// tracked + st0:4}; phase kt issues st(kt+1):4 -> vmcnt(4) retires st(kt)
// (at kt=0 also retires Q/pm/st0: 14 outstanding -> 4). kt=15: vmcnt(0).
// WAR: st(kt+1) writes buf[bu^1], last read before end-barrier(kt-1). RAW:
// post-wait s_barrier. lP is wave-private (rows w*16..w*16+15).
__global__ __launch_bounds__(256) void attn_kernel(
    const ushort_t* __restrict__ Qb, const ushort_t* __restrict__ Kb,
    const ushort_t* __restrict__ Vt, const u64_t* __restrict__ pm,
    ushort_t* __restrict__ ctx) {
  __shared__ ushort_t lK[2][4096];
  __shared__ ushort_t lVt[2][4096];
  __shared__ ushort_t lP[4096];
  const int tid = threadIdx.x;
  const int lane = tid & 63, w = tid >> 6;
  const int quad = lane >> 4, l16 = lane & 15;
  const int bid = blockIdx.x;
  const int qt = bid >> 7, pair = bid & 127;
  const int h = pair & 3, b = pair >> 2;
  const int q0 = qt * 64;
  const long qrow0 = (long)b * NQ_ + q0;
  const long krow0 = (long)b * NK_;
  const ushort_t* vbase = Vt + ((long)pair * 64) * 1024;  // [dh][kv] for this (b,h)

  // prologue: Q fragments + packed masks straight to registers (compiler-tracked)
  const int rq = w * 16 + l16;
  bf16x8 qfr[2];
#pragma unroll
  for (int ki = 0; ki < 2; ++ki)
    qfr[ki] = *(const bf16x8*)&Qb[(qrow0 + rq) * 256 + h * 64 + (ki * 4 + quad) * 8];
  u64_t pmr[4];
#pragma unroll
  for (int r = 0; r < 4; ++r)
    pmr[r] = pm[(long)(q0 + w * 16 + quad * 4 + r) * 16 + l16];

  auto stageKV = [&](int kt, int bu) {
#pragma unroll
    for (int p = 0; p < 2; ++p) {
      const int ob = p * 4096 + tid * 16;
      const int row = ob >> 7;
      const int chunk = ((ob >> 4) & 7) ^ (row & 7);
      gld16(Kb + (krow0 + kt * 64 + row) * 256 + h * 64 + chunk * 8,
            (char*)&lK[bu][0] + p * 4096 + w * 1024);
      gld16(vbase + (long)row * 1024 + kt * 64 + chunk * 8,
            (char*)&lVt[bu][0] + p * 4096 + w * 1024);
    }
  };

  f32x4 o_acc[4] = {};
  f32x4 l_acc = {};
  bf16x8 ones;
#pragma unroll
  for (int i = 0; i < 8; ++i) ones[i] = (__bf16)1.0f;

  stageKV(0, 0);

  for (int kt = 0; kt < 16; ++kt) {
    const int bu = kt & 1;
    if (kt < 15) stageKV(kt + 1, bu ^ 1);
    // retire stage(kt) (+Q/pm/st0 extras at kt=0); keep stage(kt+1) in flight
    if (kt < 15) asm volatile("s_waitcnt vmcnt(4)" ::: "memory");
    else         asm volatile("s_waitcnt vmcnt(0)" ::: "memory");
    __builtin_amdgcn_s_barrier();        // RAW: buf[bu] ready for all waves
    __builtin_amdgcn_sched_barrier(0);

    // S = Q K^T  (wave handles 16 q-rows x 64 keys); Q already carries SCALE
    f32x4 s[4] = {};
    __builtin_amdgcn_s_setprio(1);
#pragma unroll
    for (int ki = 0; ki < 2; ++ki) {
#pragma unroll
      for (int ni = 0; ni < 4; ++ni) {
        const int rk = ni * 16 + l16;
        const int ck = (ki * 4 + quad) ^ (rk & 7);
        const bf16x8 kf = *(const bf16x8*)&lK[bu][rk * 64 + ck * 8];
        s[ni] = __builtin_amdgcn_mfma_f32_16x16x32_bf16(qfr[ki], kf, s[ni], 0, 0, 0);
      }
    }
    __builtin_amdgcn_s_setprio(0);

    // P = keep ? exp(S) : 0 ; write P to LDS (swizzled A-layout, wave-private rows)
#pragma unroll
    for (int r = 0; r < 4; ++r) {
      const int rowp = w * 16 + quad * 4 + r;
#pragma unroll
      for (int ni = 0; ni < 4; ++ni) {
        const bool keep = (pmr[r] >> (kt * 4 + ni)) & 1ull;
        const float pv = keep ? __expf(s[ni][r]) : 0.f;
        const int col = ni * 16 + l16;
        lP[rowp * 64 + (((col >> 3) ^ (rowp & 7)) << 3) + (col & 7)] = f2bf(pv);
      }
    }

    // O += P V ; l += P . 1  (row sums via matrix pipe)
    __builtin_amdgcn_s_setprio(1);
#pragma unroll
    for (int ki = 0; ki < 2; ++ki) {
      const int rp = w * 16 + l16;
      const int cp = (ki * 4 + quad) ^ (rp & 7);
      const bf16x8 pf = *(const bf16x8*)&lP[rp * 64 + cp * 8];
      l_acc = __builtin_amdgcn_mfma_f32_16x16x32_bf16(pf, ones, l_acc, 0, 0, 0);
#pragma unroll
      for (int ni = 0; ni < 4; ++ni) {
        const int rv = ni * 16 + l16;
        const int cv = (ki * 4 + quad) ^ (rv & 7);
        const bf16x8 vf = *(const bf16x8*)&lVt[bu][rv * 64 + cv * 8];
        o_acc[ni] = __builtin_amdgcn_mfma_f32_16x16x32_bf16(pf, vf, o_acc[ni], 0, 0, 0);
      }
    }
    __builtin_amdgcn_s_setprio(0);
    __builtin_amdgcn_sched_barrier(0);
    __builtin_amdgcn_s_barrier();        // WAR: all reads of buf[bu] done
  }

  // normalize + write ctx (bf16)
#pragma unroll
  for (int r = 0; r < 4; ++r) {
    const float inv = 1.0f / l_acc[r];
    const long rowg = qrow0 + w * 16 + quad * 4 + r;
#pragma unroll
    for (int ni = 0; ni < 4; ++ni) {
      const int col = h * 64 + ni * 16 + l16;
      ctx[rowg * 256 + col] = f2bf(o_acc[ni][r] * inv);
    }
  }
}

extern "C" void kernel_launch(void* const* d_in, const int* in_sizes, int n_in,
                              void* d_out, int out_size, void* d_ws, size_t ws_size,
                              hipStream_t stream) {
  float* ut = (float*)d_in[0];  // mutated in place; harness restores before every launch
  const float* emb = (const float*)d_in[1];
  const float* maskl = (const float*)d_in[2];
  const float* Wq = (const float*)d_in[3];
  const float* Wk = (const float*)d_in[4];
  const float* Wv = (const float*)d_in[5];
  const float* Wo = (const float*)d_in[6];
  const float* W1 = (const float*)d_in[7];
  const float* b1 = (const float*)d_in[8];
  const float* W2 = (const float*)d_in[9];
  const float* b2 = (const float*)d_in[10];
  const float* sys_s = (const float*)d_in[11];
  const float* sys_b = (const float*)d_in[12];
  const float* eff_s = (const float*)d_in[13];
  const float* eff_b = (const float*)d_in[14];
  const float* in_s = (const float*)d_in[15];
  const float* in_b = (const float*)d_in[16];
  const float* out_s = (const float*)d_in[17];
  const float* out_b = (const float*)d_in[18];
  const int* qidx = (const int*)d_in[19];
  const int* kidx = (const int*)d_in[20];
  float* out = (float*)d_out;

  char* p = (char*)d_ws;
  auto carve = [&](size_t bytes) {
    void* r = (void*)p;
    p += (bytes + 255) & ~(size_t)255;
    return r;
  };
  ushort_t* wt = (ushort_t*)carve((size_t)6 * 65536 * 2);
  u64_t* mb = (u64_t*)carve((size_t)L_ * NQ_ * (NK_ / 64) * 8);
  u64_t* pmw = (u64_t*)carve((size_t)L_ * NQ_ * 16 * 8);
  ushort_t* qn = (ushort_t*)carve((size_t)16384 * 256 * 2);  // reused as ctx
  ushort_t* kn = (ushort_t*)carve((size_t)32768 * 256 * 2);
  ushort_t* Qb = (ushort_t*)carve((size_t)16384 * 256 * 2);  // reused as g
  ushort_t* Kb = (ushort_t*)carve((size_t)32768 * 256 * 2);  // reused as hb
  ushort_t* Vt = (ushort_t*)carve((size_t)32768 * 256 * 2);  // reused as hf (f32)

  ushort_t* ctx = qn;
  ushort_t* g = Qb;
  ushort_t* hb = Kb;
  float* hf = (float*)Vt;

  hipMemsetAsync(d_out, 0, (size_t)out_size, stream);
  prep_w<<<1536, 256, 0, stream>>>(Wq, Wk, Wv, Wo, W1, W2, wt);
  prep_mask<<<(L_ * NQ_ * NK_) / 256, 256, 0, stream>>>(maskl, mb);
  prep_mask2<<<(L_ * NQ_ * 16) / 256, 256, 0, stream>>>(mb, pmw);

  for (int l = 0; l < L_; ++l) {
    gather_ln<<<B_ * (NQ_ + NK_) / 4, 256, 0, stream>>>(
        ut, emb, qidx + l * NQ_, kidx + l * NK_, sys_s, sys_b, qn, kn);
    gemm_qkv<<<1280, 256, 0, stream>>>(qn, kn, wt, Qb, Kb, Vt);
    attn_kernel<<<1024, 256, 0, stream>>>(
        Qb, Kb, Vt, pmw + (size_t)l * NQ_ * 16, ctx);
    // Wo + inner LN fused
    gemm_band<6><<<256, 256, 0, stream>>>(
        ctx, wt + 3 * 65536, nullptr, in_s, in_b, nullptr, nullptr,
        nullptr, nullptr, hf, hb, nullptr, nullptr);
    // W1 + bias + gelu
    gemm_band<2><<<256, 256, 0, stream>>>(
        hb, wt + 4 * 65536, b1, nullptr, nullptr, nullptr, nullptr,
        nullptr, nullptr, nullptr, g, nullptr, nullptr);
    // W2 + bias + residual + outer LN + eff LN + scatter fused
    gemm_band<7><<<256, 256, 0, stream>>>(
        g, wt + 5 * 65536, b2, out_s, out_b, eff_s, eff_b,
        hf, qidx + l * NQ_, nullptr, nullptr, ut, out);
  }
}